// Round 11
// baseline (149.957 us; speedup 1.0000x reference)
//
#include <hip/hip_runtime.h>
#include <stdint.h>

// Z9QATAttention: out = softmax_causal((x@Wqkv).q @ (x@Wqkv).k^T * D^-0.5) @ v @ Wout
// charge_bias: uniform pre-mask logit shift -> softmax-invariant -> no-op.
// mask == tril -> causal predicate. Softmax scale*log2e folded into q columns in GEMM1.
// Round 11: 8-wave attn blocks (QBLK=256 supertiles): K/V staging+barriers amortize over
// 2x compute; 144 kv-tiles/bh in 16 LPT chunks -> 512 blocks x 512 thr = 2/CU, one gen.

typedef __attribute__((ext_vector_type(4))) float f32x4;
typedef __attribute__((ext_vector_type(16))) float f32x16;
typedef __attribute__((ext_vector_type(8))) __bf16 bf16x8;
typedef __attribute__((ext_vector_type(8))) unsigned short ushort8;
typedef __attribute__((ext_vector_type(4))) unsigned short ushort4v;
typedef __attribute__((ext_vector_type(4))) unsigned int uint4v;

#define DEV __device__ __forceinline__

DEV unsigned short f32_to_bf16(float f) {
    union { float f; unsigned int u; } cv; cv.f = f;
    unsigned int u = cv.u;
    return (unsigned short)((u + 0x7FFFu + ((u >> 16) & 1u)) >> 16);
}

DEV float bf16_to_f32(unsigned short u) {
    union { unsigned int i; float f; } cv; cv.i = ((unsigned int)u) << 16;
    return cv.f;
}

DEV bf16x8 load_bf16x8(const unsigned short* p) {
    ushort8 v = *(const ushort8*)p;
    return __builtin_bit_cast(bf16x8, v);
}

DEV unsigned cvt_pk_bf16(float lo, float hi) {
    unsigned r;
    asm("v_cvt_pk_bf16_f32 %0, %1, %2" : "=v"(r) : "v"(lo), "v"(hi));
    return r;
}

DEV void gload_lds16(const void* g, void* l) {
    __builtin_amdgcn_global_load_lds(
        (const __attribute__((address_space(1))) unsigned int*)g,
        (__attribute__((address_space(3))) unsigned int*)l, 16, 0, 0);
}

DEV f32x16 vzero16() {
    f32x16 v;
#pragma unroll
    for (int i = 0; i < 16; ++i) v[i] = 0.f;
    return v;
}

// tree reductions over the 32 S values (depth 5 instead of 31-deep chains)
DEV float tmax32(const f32x16& a, const f32x16& b) {
    float m[16];
#pragma unroll
    for (int i = 0; i < 16; ++i) m[i] = fmaxf(a[i], b[i]);
#pragma unroll
    for (int st = 8; st > 0; st >>= 1)
#pragma unroll
        for (int i = 0; i < 8; ++i) if (i < st) m[i] = fmaxf(m[i], m[i + st]);
    return m[0];
}
DEV float tsum32(const f32x16& a, const f32x16& b) {
    float m[16];
#pragma unroll
    for (int i = 0; i < 16; ++i) m[i] = a[i] + b[i];
#pragma unroll
    for (int st = 8; st > 0; st >>= 1)
#pragma unroll
        for (int i = 0; i < 8; ++i) if (i < st) m[i] = m[i] + m[i + st];
    return m[0];
}

// ---- 8-wave supertile work tables: 16 items per (b,h), LPT order. ----
// Supertile Q covers q-rows [Q*256, Q*256+256); kv tiles needed = 4Q+4.
// Chunks: Q7:8+8+8+8  Q6:10+9+9  Q5:12+12  Q4:10+10  Q3:8+8  Q2:12  Q1:8  Q0:4 (sum 144).
// mlS: m/l slot (255 = full supertile, normalize in-kernel). obS: Obuf slot (255 = c0 ->
// write unnormalized to attn natural location; combine renormalizes in place).
__device__ __constant__ unsigned char qS[16]  = {5, 5, 2, 6, 4, 4, 6, 6, 7, 7, 7, 7, 3, 3, 1, 0};
__device__ __constant__ unsigned char tsS[16] = {0,12, 0, 0, 0,10,10,19, 0, 8,16,24, 0, 8, 0, 0};
__device__ __constant__ unsigned char teS[16] = {12,24,12,10,10,20,19,28, 8,16,24,32, 8,16, 8, 4};
__device__ __constant__ unsigned char mlS[16] = {7, 8,255, 4, 9,10, 5, 6, 0, 1, 2, 3,11,12,255,255};
__device__ __constant__ unsigned char obS[16] = {255,5,255,255,255,6, 3, 4,255, 0, 1, 2,255, 7,255,255};
// combine tables: split supertiles s=0..4 -> Q = {7,6,5,4,3}
__device__ __constant__ unsigned char qs4[5]   = {7,6,5,4,3};
__device__ __constant__ unsigned char ncs4[5]  = {4,3,2,2,2};
__device__ __constant__ unsigned char mlbs4[5] = {0,4,7,9,11};
__device__ __constant__ unsigned char obbs4[5] = {0,3,5,6,7};

// ---------------- fp32 -> bf16 conversion (8 elems/thread) ----------------
__global__ void cvt_kernel(const float* __restrict__ in, unsigned short* __restrict__ out, int n) {
    int i = (blockIdx.x * blockDim.x + threadIdx.x) * 8;
    if (i >= n) return;
    f32x4 a = *(const f32x4*)(in + i);
    f32x4 b = *(const f32x4*)(in + i + 4);
    ushort8 o;
    o[0] = f32_to_bf16(a[0]); o[1] = f32_to_bf16(a[1]);
    o[2] = f32_to_bf16(a[2]); o[3] = f32_to_bf16(a[3]);
    o[4] = f32_to_bf16(b[0]); o[5] = f32_to_bf16(b[1]);
    o[6] = f32_to_bf16(b[2]); o[7] = f32_to_bf16(b[3]);
    *(ushort8*)(out + i) = o;
}

// ---------------- fp32 -> bf16 transpose: out[c][r] = bf16(in[r][c]) ----------------
__global__ __launch_bounds__(256) void tcvt_kernel(const float* __restrict__ in,
                                                   unsigned short* __restrict__ out,
                                                   int R, int Cn) {
    __shared__ float tl[32][33];
    const int tx = threadIdx.x & 31, ty = threadIdx.x >> 5;
    const int c0 = blockIdx.x * 32, r0 = blockIdx.y * 32;
#pragma unroll
    for (int rr = 0; rr < 4; ++rr) {
        int r = ty + rr * 8;
        tl[r][tx] = in[(size_t)(r0 + r) * Cn + c0 + tx];
    }
    __syncthreads();
#pragma unroll
    for (int rr = 0; rr < 4; ++rr) {
        int cc = ty + rr * 8;
        out[(size_t)(c0 + cc) * R + r0 + tx] = f32_to_bf16(tl[tx][cc]);
    }
}

// ---------------- bf16 MFMA GEMM, counted-vmcnt depth-2 pipeline: C = A @ Bt^T ----------------
template<bool OUT_BF16, bool SCALE_Q>
__global__ __launch_bounds__(256) void gemm_kernel(
    const unsigned short* __restrict__ A,
    const unsigned short* __restrict__ Bt,
    void* __restrict__ C, int K, int ldc)
{
    __shared__ __align__(16) unsigned short As[3][4096];
    __shared__ __align__(16) unsigned short Bs[3][4096];

    const int tid = threadIdx.x;
    const int lane = tid & 63;
    const int w = tid >> 6;
    const int wr = w >> 1, wc = w & 1;
    const int g = lane >> 4, ci = lane & 15;
    const int bx = blockIdx.x, by = blockIdx.y;
    const int soff = w * 1024 + lane * 16;
    const int srow = soff >> 6;
    const int scch = (soff >> 4) & 3;

#define GSTAGE(buf, k0_) do { \
    _Pragma("unroll") for (int i_ = 0; i_ < 2; ++i_) { \
        int row_ = srow + i_ * 64; \
        gload_lds16(A  + (size_t)(by * 128 + row_) * K + (k0_) + scch * 8, \
                    (char*)As[buf] + i_ * 4096 + w * 1024); \
        gload_lds16(Bt + (size_t)(bx * 128 + row_) * K + (k0_) + scch * 8, \
                    (char*)Bs[buf] + i_ * 4096 + w * 1024); } } while (0)

    f32x4 acc[4][4];
#pragma unroll
    for (int i = 0; i < 4; ++i)
#pragma unroll
        for (int j = 0; j < 4; ++j) acc[i][j] = f32x4{0.f, 0.f, 0.f, 0.f};

    const int nk = K >> 5;
    GSTAGE(0, 0);
    GSTAGE(1, 32);
    asm volatile("s_waitcnt vmcnt(4)" ::: "memory");
    __builtin_amdgcn_sched_barrier(0);
    __builtin_amdgcn_s_barrier();
    __builtin_amdgcn_sched_barrier(0);

    for (int kt = 0; kt < nk; ++kt) {
        const int cur = kt % 3;
        if (kt + 2 < nk) GSTAGE((kt + 2) % 3, (kt + 2) << 5);

        bf16x8 af[4], bfr[4];
#pragma unroll
        for (int mf = 0; mf < 4; ++mf) af[mf]  = load_bf16x8(&As[cur][(wr * 64 + mf * 16 + ci) * 32 + g * 8]);
#pragma unroll
        for (int nf = 0; nf < 4; ++nf) bfr[nf] = load_bf16x8(&Bs[cur][(wc * 64 + nf * 16 + ci) * 32 + g * 8]);
        __builtin_amdgcn_s_setprio(1);
#pragma unroll
        for (int mf = 0; mf < 4; ++mf)
#pragma unroll
            for (int nf = 0; nf < 4; ++nf)
                acc[mf][nf] = __builtin_amdgcn_mfma_f32_16x16x32_bf16(af[mf], bfr[nf], acc[mf][nf], 0, 0, 0);
        __builtin_amdgcn_s_setprio(0);

        if (kt + 2 < nk) asm volatile("s_waitcnt vmcnt(4) lgkmcnt(0)" ::: "memory");
        else             asm volatile("s_waitcnt vmcnt(0) lgkmcnt(0)" ::: "memory");
        __builtin_amdgcn_sched_barrier(0);
        __builtin_amdgcn_s_barrier();
        __builtin_amdgcn_sched_barrier(0);
    }
#undef GSTAGE

#pragma unroll
    for (int mf = 0; mf < 4; ++mf)
#pragma unroll
        for (int nf = 0; nf < 4; ++nf)
#pragma unroll
            for (int r = 0; r < 4; ++r) {
                int row = by * 128 + wr * 64 + mf * 16 + g * 4 + r;
                int col = bx * 128 + wc * 64 + nf * 16 + ci;
                float v = acc[mf][nf][r];
                if (SCALE_Q && col < 1024) v *= 0.1803368801f;  // D^-0.5 * log2(e)
                if (OUT_BF16)
                    ((unsigned short*)C)[(size_t)row * ldc + col] = f32_to_bf16(v);
                else
                    ((float*)C)[(size_t)row * ldc + col] = v;
            }
}

// ---------------- causal flash attention, 8-wave supertiles, depth-2 pipeline ----------------
__global__ __launch_bounds__(512, 4) void attn8_kernel(const unsigned short* __restrict__ qkv,
                                                       unsigned short* __restrict__ attn,
                                                       unsigned short* __restrict__ Obuf,
                                                       float* __restrict__ mlbuf) {
    constexpr int T = 2048, HD3 = 3072, Cc = 1024;
    __shared__ __align__(16) unsigned short Ks[3][4096];  // [64 kv][64 d], col ^= (row&7)*8
    __shared__ __align__(16) unsigned short Vt[2][4096];  // [64 d][64 kv], col ^= ((d^(d>>3))&7)*8

    const int tid = threadIdx.x;
    const int lane = tid & 63;
    const int w = tid >> 6;          // 0..7
    const int l31 = lane & 31;
    const int hi = lane >> 5;

    const int bx = blockIdx.x;
    const int j = bx >> 5;            // 0..15 (LPT-ordered work item)
    const int bh = bx & 31;
    const int q = qS[j];              // supertile (256 q-rows)
    const int ts = tsS[j], te = teS[j];
    const int h = bh & 15;
    const int b = bh >> 4;
    const int q0w = q * 256 + w * 32;
    const int qrow = q0w + l31;
    const size_t base = (size_t)b * T * HD3;
    const int ntc = te - ts;          // >= 4 always

    bf16x8 qf[4];   // B-operand: lane holds Q[qrow][t*16 + hi*8 + jj] (q pre-scaled in GEMM1)
#pragma unroll
    for (int t = 0; t < 4; ++t)
        qf[t] = load_bf16x8(qkv + base + (size_t)qrow * HD3 + h * 64 + t * 16 + hi * 8);

    f32x16 acc0 = vzero16(), acc1 = vzero16();  // O^T: col=q(lane), row d = rr+8G+4hi (+32)
    float m = -3e38f, l = 0.f;

    ushort8 vA0, vB0;
// 512 threads: 1 x 16B gload_lds per thread stages a full 64x64 tile (8 KB).
#define LOADV(tile, r0) do { int kv0_ = (tile) * 64; \
    int rr0_ = tid >> 3, cc0_ = tid & 7; \
    r0 = *(const ushort8*)(qkv + base + (size_t)(kv0_ + rr0_) * HD3 + 2 * Cc + h * 64 + cc0_ * 8); } while (0)

#define DMAK(tile, kb) do { int kv0_ = (tile) * 64; \
    int row_ = tid >> 3; \
    int csw_ = (((tid & 7) * 8) ^ ((row_ & 7) * 8)); \
    gload_lds16(qkv + base + (size_t)(kv0_ + row_) * HD3 + Cc + h * 64 + csw_, \
                (void*)(((char*)&Ks[kb][0]) + tid * 16)); } while (0)

#define WRITEV(vb, r0) do { \
    int row_ = tid >> 3, cc_ = tid & 7; \
    _Pragma("unroll") for (int j_ = 0; j_ < 8; ++j_) { \
        int d_ = cc_ * 8 + j_; \
        int sw_ = ((d_ ^ (d_ >> 3)) & 7) * 8; \
        Vt[vb][d_ * 64 + (row_ ^ sw_)] = r0[j_]; } } while (0)

    // prologue: tile ts fully staged; tile ts+1 in flight
    LOADV(ts, vA0);
    DMAK(ts, 0);
    asm volatile("s_waitcnt vmcnt(0)" ::: "memory");
    __builtin_amdgcn_sched_barrier(0);
    WRITEV(0, vA0);
    LOADV(ts + 1, vB0);
    DMAK(ts + 1, 1);
    asm volatile("s_waitcnt lgkmcnt(0)" ::: "memory");
    __builtin_amdgcn_sched_barrier(0);
    __builtin_amdgcn_s_barrier();
    __builtin_amdgcn_sched_barrier(0);

    for (int tt = 0; tt < ntc; ++tt) {
        const int t = ts + tt;
        const int kv0 = t * 64;
        const int kcur = tt % 3;
        const int vcur = tt & 1;
        const bool act = (kv0 <= q0w + 31);
        const bool pre2 = (tt + 2) < ntc;

        // 1. write V(t+1) to LDS (regs 1 tile old -> implicit vmem wait here is free)
        if (tt + 1 < ntc) {
            if (tt & 1) WRITEV(vcur ^ 1, vA0); else WRITEV(vcur ^ 1, vB0);
        }
        // 2. issue prefetch for tile t+2 (V->regs, K->LDS buf (tt+2)%3)
        if (pre2) {
            if (tt & 1) LOADV(t + 2, vB0); else LOADV(t + 2, vA0);
            DMAK(t + 2, (tt + 2) % 3);
        }

        if (act) {
            f32x16 s0 = vzero16(), s1 = vzero16();
            bf16x8 pf[4];
            const bool st1_ok = (kv0 + 32 <= q0w + 31);
            __builtin_amdgcn_s_setprio(1);
#pragma unroll
            for (int tf = 0; tf < 4; ++tf) {  // st = 0
                int row = l31;
                int idx = kcur * 4096 + row * 64 + ((tf * 16 + hi * 8) ^ ((row & 7) * 8));
                s0 = __builtin_amdgcn_mfma_f32_32x32x16_bf16(load_bf16x8(&Ks[0][idx]), qf[tf], s0, 0, 0, 0);
            }
            if (st1_ok) {
#pragma unroll
                for (int tf = 0; tf < 4; ++tf) {  // st = 1
                    int row = 32 + l31;
                    int idx = kcur * 4096 + row * 64 + ((tf * 16 + hi * 8) ^ ((row & 7) * 8));
                    s1 = __builtin_amdgcn_mfma_f32_32x32x16_bf16(load_bf16x8(&Ks[0][idx]), qf[tf], s1, 0, 0, 0);
                }
            }
            __builtin_amdgcn_s_setprio(0);
            const bool needmask = (kv0 + 63 > q0w);
            if (needmask) {
#pragma unroll
                for (int G = 0; G < 4; ++G)
#pragma unroll
                    for (int rr = 0; rr < 4; ++rr) {
                        int kvb = kv0 + 8 * G + 4 * hi + rr;  // kv of C-reg (crow formula, HW-verified)
                        s0[G * 4 + rr] = (kvb      <= qrow) ? s0[G * 4 + rr] : -3e38f;
                        s1[G * 4 + rr] = (kvb + 32 <= qrow) ? s1[G * 4 + rr] : -3e38f;
                    }
            }
            float pmax = tmax32(s0, s1);
            pmax = fmaxf(pmax, __shfl_xor(pmax, 32));   // HW-verified exchange
            // defer-max (T13): skip O/l rescale while pmax - m <= 11.5 (log2 domain)
            if (!__all(pmax - m <= 11.5f)) {
                float mnew = fmaxf(m, pmax);
                float alpha = exp2f(m - mnew);
                m = mnew;
                l *= alpha;
#pragma unroll
                for (int i = 0; i < 16; ++i) { acc0[i] *= alpha; acc1[i] *= alpha; }
            }
#pragma unroll
            for (int i = 0; i < 16; ++i) {
                s0[i] = exp2f(s0[i] - m);
                s1[i] = exp2f(s1[i] - m);
            }

            // P -> B-fragments (cvt_pk + lane<->lane+32 exchange, HW-verified construction)
            unsigned pk0[4][2], pk1[4][2];
#pragma unroll
            for (int G = 0; G < 4; ++G) {
                pk0[G][0] = cvt_pk_bf16(s0[G * 4 + 0], s0[G * 4 + 1]);
                pk0[G][1] = cvt_pk_bf16(s0[G * 4 + 2], s0[G * 4 + 3]);
                pk1[G][0] = cvt_pk_bf16(s1[G * 4 + 0], s1[G * 4 + 1]);
                pk1[G][1] = cvt_pk_bf16(s1[G * 4 + 2], s1[G * 4 + 3]);
            }
#pragma unroll
            for (int tf = 0; tf < 4; ++tf) {
                const int kb = tf & 1;
                unsigned sA0, sA1, sB0, sB1;
                if (tf < 2) { sA0 = pk0[2 * kb][0]; sA1 = pk0[2 * kb][1]; sB0 = pk0[2 * kb + 1][0]; sB1 = pk0[2 * kb + 1][1]; }
                else        { sA0 = pk1[2 * kb][0]; sA1 = pk1[2 * kb][1]; sB0 = pk1[2 * kb + 1][0]; sB1 = pk1[2 * kb + 1][1]; }
                unsigned sd0 = hi ? sA0 : sB0, sd1 = hi ? sA1 : sB1;
                unsigned rc0 = (unsigned)__shfl_xor((int)sd0, 32);
                unsigned rc1 = (unsigned)__shfl_xor((int)sd1, 32);
                uint4v u;
                u[0] = hi ? rc0 : sA0;  u[1] = hi ? rc1 : sA1;   // k = hi*8 + 0..3
                u[2] = hi ? sB0 : rc0;  u[3] = hi ? sB1 : rc1;   // k = hi*8 + 4..7
                pf[tf] = __builtin_bit_cast(bf16x8, u);
            }

            __builtin_amdgcn_s_setprio(1);
#pragma unroll
            for (int tf = 0; tf < 4; ++tf) {
                {
                    int d = l31, sw = ((d ^ (d >> 3)) & 7) * 8;
                    bf16x8 vf = load_bf16x8(&Vt[vcur][d * 64 + ((tf * 16 + hi * 8) ^ sw)]);
                    acc0 = __builtin_amdgcn_mfma_f32_32x32x16_bf16(vf, pf[tf], acc0, 0, 0, 0);
                }
                {
                    int d = 32 + l31, sw = ((d ^ (d >> 3)) & 7) * 8;
                    bf16x8 vf = load_bf16x8(&Vt[vcur][d * 64 + ((tf * 16 + hi * 8) ^ sw)]);
                    acc1 = __builtin_amdgcn_mfma_f32_32x32x16_bf16(vf, pf[tf], acc1, 0, 0, 0);
                }
            }
            __builtin_amdgcn_s_setprio(0);

            // row-sum + l update off the PV critical path
            float rsum = tsum32(s0, s1);
            l += rsum + __shfl_xor(rsum, 32);
        }

        // counted-vmcnt barrier: guarantee K(t+1) landed, keep t+2 prefetch in flight
        if (pre2) asm volatile("s_waitcnt vmcnt(2) lgkmcnt(0)" ::: "memory");
        else      asm volatile("s_waitcnt vmcnt(0) lgkmcnt(0)" ::: "memory");
        __builtin_amdgcn_sched_barrier(0);
        __builtin_amdgcn_s_barrier();
        __builtin_amdgcn_sched_barrier(0);
    }

    const int mlq = mlS[j], obq = obS[j];
    const int qlocal = w * 32 + l31;   // 0..255
    if (mlq == 255) {
        // full supertile: normalize and write attn
        const float invl = 1.0f / l;
        const size_t ob = (size_t)b * T * Cc + (size_t)qrow * Cc + h * 64;
#pragma unroll
        for (int G = 0; G < 4; ++G) {
            ushort4v o0, o1;
#pragma unroll
            for (int rr = 0; rr < 4; ++rr) {
                o0[rr] = f32_to_bf16(acc0[G * 4 + rr] * invl);
                o1[rr] = f32_to_bf16(acc1[G * 4 + rr] * invl);
            }
            int d0 = 8 * G + 4 * hi;
            *(ushort4v*)(attn + ob + d0) = o0;
            *(ushort4v*)(attn + ob + 32 + d0) = o1;
        }
    } else {
        // chunk: write unnormalized partial O; c0 goes to attn natural location
        unsigned short* op = (obq == 255)
            ? (attn + (size_t)b * T * Cc + (size_t)qrow * Cc + h * 64)
            : (Obuf + (size_t)(bh * 8 + obq) * 16384 + qlocal * 64);
#pragma unroll
        for (int G = 0; G < 4; ++G) {
            ushort4v o0, o1;
#pragma unroll
            for (int rr = 0; rr < 4; ++rr) {
                o0[rr] = f32_to_bf16(acc0[G * 4 + rr]);
                o1[rr] = f32_to_bf16(acc1[G * 4 + rr]);
            }
            int d0 = 8 * G + 4 * hi;
            *(ushort4v*)(op + d0) = o0;
            *(ushort4v*)(op + 32 + d0) = o1;
        }
        if (hi == 0) {
            float* mp = mlbuf + (size_t)(bh * 13 + mlq) * 512 + qlocal * 2;
            mp[0] = m; mp[1] = l;
        }
    }
#undef LOADV
#undef DMAK
#undef WRITEV
}

// ---------------- combine: merge up to 4 kv-chunks of each split supertile ----------------
__global__ __launch_bounds__(256) void combine4_kernel(const unsigned short* __restrict__ Obuf,
                                                       const float* __restrict__ mlbuf,
                                                       unsigned short* __restrict__ attn) {
    constexpr int T = 2048, Cc = 1024;
    const int ss = blockIdx.x;            // 0..159: (bh, s)
    const int bh = ss / 5, s = ss - bh * 5;
    const int q = qs4[s];
    const int nc = ncs4[s], mlb = mlbs4[s], obb = obbs4[s];
    const int b = bh >> 4, h = bh & 15;
    const int qlocal = threadIdx.x;       // 0..255

    float mv[4], lv[4];
#pragma unroll
    for (int c = 0; c < 4; ++c) {
        mv[c] = -3e38f; lv[c] = 0.f;
        if (c < nc) {
            const float* mp = mlbuf + (size_t)(bh * 13 + mlb + c) * 512 + qlocal * 2;
            mv[c] = mp[0]; lv[c] = mp[1];
        }
    }
    float M = fmaxf(fmaxf(mv[0], mv[1]), fmaxf(mv[2], mv[3]));
    float fc[4];
    float denom = 0.f;
#pragma unroll
    for (int c = 0; c < 4; ++c) {
        fc[c] = (c < nc) ? exp2f(mv[c] - M) : 0.f;
        denom += fc[c] * lv[c];
    }
    const float inv = 1.f / denom;
#pragma unroll
    for (int c = 0; c < 4; ++c) fc[c] *= inv;

    unsigned short* po = attn + (size_t)b * T * Cc + (size_t)(q * 256 + qlocal) * Cc + h * 64;
#pragma unroll
    for (int i = 0; i < 8; ++i) {
        float acc[8] = {0.f, 0.f, 0.f, 0.f, 0.f, 0.f, 0.f, 0.f};
#pragma unroll
        for (int c = 0; c < 4; ++c) {
            if (c < nc) {
                const unsigned short* pc = (c == 0)
                    ? po
                    : (Obuf + (size_t)(bh * 8 + obb + c - 1) * 16384 + qlocal * 64);
                ushort8 a = *(const ushort8*)(pc + i * 8);
#pragma unroll
                for (int k = 0; k < 8; ++k) acc[k] += fc[c] * bf16_to_f32(a[k]);
            }
        }
        ushort8 o;
#pragma unroll
        for (int k = 0; k < 8; ++k) o[k] = f32_to_bf16(acc[k]);
        *(ushort8*)(po + i * 8) = o;
    }
}

extern "C" void kernel_launch(void* const* d_in, const int* in_sizes, int n_in,
                              void* d_out, int out_size, void* d_ws, size_t ws_size,
                              hipStream_t stream) {
    const float* x     = (const float*)d_in[0];
    // d_in[1] = mask (tril -> causal predicate), unused
    const float* w_qkv = (const float*)d_in[2];
    const float* w_out = (const float*)d_in[3];
    // d_in[4] = charge_w: provably no-op, unused
    float* out = (float*)d_out;

    // workspace (bf16 elements)
    unsigned short* xb     = (unsigned short*)d_ws;
    unsigned short* wqkvT  = xb + 4194304;        // [3072][1024]
    unsigned short* woutT  = wqkvT + 3145728;     // [1024][1024]
    unsigned short* qkv    = woutT + 1048576;     // [4096][3072]
    unsigned short* attn   = qkv + 12582912;      // [4096][1024]
    // partials alias regions dead after GEMM1: Obuf = 32bh x 8 slots x 16384 = 4194304
    // elements (exactly the xb region); mlbuf = 32 x 13 x 512 fp32 at wqkvT start.
    unsigned short* Obuf   = xb;
    float*          mlbuf  = (float*)wqkvT;

    cvt_kernel<<<2048, 256, 0, stream>>>(x, xb, 4194304);
    tcvt_kernel<<<dim3(96, 32), 256, 0, stream>>>(w_qkv, wqkvT, 1024, 3072);
    tcvt_kernel<<<dim3(32, 32), 256, 0, stream>>>(w_out, woutT, 1024, 1024);

    // qkv = xb @ w_qkv (M=4096, N=3072, K=1024), bf16 out, q-columns pre-scaled
    gemm_kernel<true, true><<<dim3(24, 32), 256, 0, stream>>>(xb, wqkvT, (void*)qkv, 1024, 3072);

    // causal attention: 512 LPT-ordered 8-wave blocks (16 supertile-chunks x 32 bh)
    attn8_kernel<<<512, 512, 0, stream>>>(qkv, attn, Obuf, mlbuf);
    combine4_kernel<<<160, 256, 0, stream>>>(Obuf, mlbuf, attn);

    // out = attn @ w_out (M=4096, N=1024, K=1024), fp32 out
    gemm_kernel<false, false><<<dim3(8, 32), 256, 0, stream>>>(attn, woutT, (void*)out, 1024, 1024);
}

// Round 12
// 144.738 us; speedup vs baseline: 1.0361x; 1.0361x over previous
//
#include <hip/hip_runtime.h>
#include <stdint.h>

// Z9QATAttention: out = softmax_causal((x@Wqkv).q @ (x@Wqkv).k^T * D^-0.5) @ v @ Wout
// charge_bias: uniform pre-mask logit shift -> softmax-invariant -> no-op.
// mask == tril -> causal predicate. Softmax scale*log2e folded into q columns in GEMM1.
// Round 12: round-11 8-wave structure with the launch-bounds spill fix:
// __launch_bounds__(512,2) (VGPR cap 256, compiler uses ~112) -> no scratch spills.

typedef __attribute__((ext_vector_type(4))) float f32x4;
typedef __attribute__((ext_vector_type(16))) float f32x16;
typedef __attribute__((ext_vector_type(8))) __bf16 bf16x8;
typedef __attribute__((ext_vector_type(8))) unsigned short ushort8;
typedef __attribute__((ext_vector_type(4))) unsigned short ushort4v;
typedef __attribute__((ext_vector_type(4))) unsigned int uint4v;

#define DEV __device__ __forceinline__

DEV unsigned short f32_to_bf16(float f) {
    union { float f; unsigned int u; } cv; cv.f = f;
    unsigned int u = cv.u;
    return (unsigned short)((u + 0x7FFFu + ((u >> 16) & 1u)) >> 16);
}

DEV float bf16_to_f32(unsigned short u) {
    union { unsigned int i; float f; } cv; cv.i = ((unsigned int)u) << 16;
    return cv.f;
}

DEV bf16x8 load_bf16x8(const unsigned short* p) {
    ushort8 v = *(const ushort8*)p;
    return __builtin_bit_cast(bf16x8, v);
}

DEV unsigned cvt_pk_bf16(float lo, float hi) {
    unsigned r;
    asm("v_cvt_pk_bf16_f32 %0, %1, %2" : "=v"(r) : "v"(lo), "v"(hi));
    return r;
}

DEV void gload_lds16(const void* g, void* l) {
    __builtin_amdgcn_global_load_lds(
        (const __attribute__((address_space(1))) unsigned int*)g,
        (__attribute__((address_space(3))) unsigned int*)l, 16, 0, 0);
}

DEV f32x16 vzero16() {
    f32x16 v;
#pragma unroll
    for (int i = 0; i < 16; ++i) v[i] = 0.f;
    return v;
}

// tree reductions over the 32 S values (depth 5 instead of 31-deep chains)
DEV float tmax32(const f32x16& a, const f32x16& b) {
    float m[16];
#pragma unroll
    for (int i = 0; i < 16; ++i) m[i] = fmaxf(a[i], b[i]);
#pragma unroll
    for (int st = 8; st > 0; st >>= 1)
#pragma unroll
        for (int i = 0; i < 8; ++i) if (i < st) m[i] = fmaxf(m[i], m[i + st]);
    return m[0];
}
DEV float tsum32(const f32x16& a, const f32x16& b) {
    float m[16];
#pragma unroll
    for (int i = 0; i < 16; ++i) m[i] = a[i] + b[i];
#pragma unroll
    for (int st = 8; st > 0; st >>= 1)
#pragma unroll
        for (int i = 0; i < 8; ++i) if (i < st) m[i] = m[i] + m[i + st];
    return m[0];
}

// ---- 8-wave supertile work tables: 16 items per (b,h), LPT order. ----
// Supertile Q covers q-rows [Q*256, Q*256+256); kv tiles needed = 4Q+4.
// Chunks: Q7:8+8+8+8  Q6:10+9+9  Q5:12+12  Q4:10+10  Q3:8+8  Q2:12  Q1:8  Q0:4 (sum 144).
// mlS: m/l slot (255 = full supertile, normalize in-kernel). obS: Obuf slot (255 = c0 ->
// write unnormalized to attn natural location; combine renormalizes in place).
__device__ __constant__ unsigned char qS[16]  = {5, 5, 2, 6, 4, 4, 6, 6, 7, 7, 7, 7, 3, 3, 1, 0};
__device__ __constant__ unsigned char tsS[16] = {0,12, 0, 0, 0,10,10,19, 0, 8,16,24, 0, 8, 0, 0};
__device__ __constant__ unsigned char teS[16] = {12,24,12,10,10,20,19,28, 8,16,24,32, 8,16, 8, 4};
__device__ __constant__ unsigned char mlS[16] = {7, 8,255, 4, 9,10, 5, 6, 0, 1, 2, 3,11,12,255,255};
__device__ __constant__ unsigned char obS[16] = {255,5,255,255,255,6, 3, 4,255, 0, 1, 2,255, 7,255,255};
// combine tables: split supertiles s=0..4 -> Q = {7,6,5,4,3}
__device__ __constant__ unsigned char qs4[5]   = {7,6,5,4,3};
__device__ __constant__ unsigned char ncs4[5]  = {4,3,2,2,2};
__device__ __constant__ unsigned char mlbs4[5] = {0,4,7,9,11};
__device__ __constant__ unsigned char obbs4[5] = {0,3,5,6,7};

// ---------------- fp32 -> bf16 conversion (8 elems/thread) ----------------
__global__ void cvt_kernel(const float* __restrict__ in, unsigned short* __restrict__ out, int n) {
    int i = (blockIdx.x * blockDim.x + threadIdx.x) * 8;
    if (i >= n) return;
    f32x4 a = *(const f32x4*)(in + i);
    f32x4 b = *(const f32x4*)(in + i + 4);
    ushort8 o;
    o[0] = f32_to_bf16(a[0]); o[1] = f32_to_bf16(a[1]);
    o[2] = f32_to_bf16(a[2]); o[3] = f32_to_bf16(a[3]);
    o[4] = f32_to_bf16(b[0]); o[5] = f32_to_bf16(b[1]);
    o[6] = f32_to_bf16(b[2]); o[7] = f32_to_bf16(b[3]);
    *(ushort8*)(out + i) = o;
}

// ---------------- fp32 -> bf16 transpose: out[c][r] = bf16(in[r][c]) ----------------
__global__ __launch_bounds__(256) void tcvt_kernel(const float* __restrict__ in,
                                                   unsigned short* __restrict__ out,
                                                   int R, int Cn) {
    __shared__ float tl[32][33];
    const int tx = threadIdx.x & 31, ty = threadIdx.x >> 5;
    const int c0 = blockIdx.x * 32, r0 = blockIdx.y * 32;
#pragma unroll
    for (int rr = 0; rr < 4; ++rr) {
        int r = ty + rr * 8;
        tl[r][tx] = in[(size_t)(r0 + r) * Cn + c0 + tx];
    }
    __syncthreads();
#pragma unroll
    for (int rr = 0; rr < 4; ++rr) {
        int cc = ty + rr * 8;
        out[(size_t)(c0 + cc) * R + r0 + tx] = f32_to_bf16(tl[tx][cc]);
    }
}

// ---------------- bf16 MFMA GEMM, counted-vmcnt depth-2 pipeline: C = A @ Bt^T ----------------
template<bool OUT_BF16, bool SCALE_Q>
__global__ __launch_bounds__(256) void gemm_kernel(
    const unsigned short* __restrict__ A,
    const unsigned short* __restrict__ Bt,
    void* __restrict__ C, int K, int ldc)
{
    __shared__ __align__(16) unsigned short As[3][4096];
    __shared__ __align__(16) unsigned short Bs[3][4096];

    const int tid = threadIdx.x;
    const int lane = tid & 63;
    const int w = tid >> 6;
    const int wr = w >> 1, wc = w & 1;
    const int g = lane >> 4, ci = lane & 15;
    const int bx = blockIdx.x, by = blockIdx.y;
    const int soff = w * 1024 + lane * 16;
    const int srow = soff >> 6;
    const int scch = (soff >> 4) & 3;

#define GSTAGE(buf, k0_) do { \
    _Pragma("unroll") for (int i_ = 0; i_ < 2; ++i_) { \
        int row_ = srow + i_ * 64; \
        gload_lds16(A  + (size_t)(by * 128 + row_) * K + (k0_) + scch * 8, \
                    (char*)As[buf] + i_ * 4096 + w * 1024); \
        gload_lds16(Bt + (size_t)(bx * 128 + row_) * K + (k0_) + scch * 8, \
                    (char*)Bs[buf] + i_ * 4096 + w * 1024); } } while (0)

    f32x4 acc[4][4];
#pragma unroll
    for (int i = 0; i < 4; ++i)
#pragma unroll
        for (int j = 0; j < 4; ++j) acc[i][j] = f32x4{0.f, 0.f, 0.f, 0.f};

    const int nk = K >> 5;
    GSTAGE(0, 0);
    GSTAGE(1, 32);
    asm volatile("s_waitcnt vmcnt(4)" ::: "memory");
    __builtin_amdgcn_sched_barrier(0);
    __builtin_amdgcn_s_barrier();
    __builtin_amdgcn_sched_barrier(0);

    for (int kt = 0; kt < nk; ++kt) {
        const int cur = kt % 3;
        if (kt + 2 < nk) GSTAGE((kt + 2) % 3, (kt + 2) << 5);

        bf16x8 af[4], bfr[4];
#pragma unroll
        for (int mf = 0; mf < 4; ++mf) af[mf]  = load_bf16x8(&As[cur][(wr * 64 + mf * 16 + ci) * 32 + g * 8]);
#pragma unroll
        for (int nf = 0; nf < 4; ++nf) bfr[nf] = load_bf16x8(&Bs[cur][(wc * 64 + nf * 16 + ci) * 32 + g * 8]);
        __builtin_amdgcn_s_setprio(1);
#pragma unroll
        for (int mf = 0; mf < 4; ++mf)
#pragma unroll
            for (int nf = 0; nf < 4; ++nf)
                acc[mf][nf] = __builtin_amdgcn_mfma_f32_16x16x32_bf16(af[mf], bfr[nf], acc[mf][nf], 0, 0, 0);
        __builtin_amdgcn_s_setprio(0);

        if (kt + 2 < nk) asm volatile("s_waitcnt vmcnt(4) lgkmcnt(0)" ::: "memory");
        else             asm volatile("s_waitcnt vmcnt(0) lgkmcnt(0)" ::: "memory");
        __builtin_amdgcn_sched_barrier(0);
        __builtin_amdgcn_s_barrier();
        __builtin_amdgcn_sched_barrier(0);
    }
#undef GSTAGE

#pragma unroll
    for (int mf = 0; mf < 4; ++mf)
#pragma unroll
        for (int nf = 0; nf < 4; ++nf)
#pragma unroll
            for (int r = 0; r < 4; ++r) {
                int row = by * 128 + wr * 64 + mf * 16 + g * 4 + r;
                int col = bx * 128 + wc * 64 + nf * 16 + ci;
                float v = acc[mf][nf][r];
                if (SCALE_Q && col < 1024) v *= 0.1803368801f;  // D^-0.5 * log2(e)
                if (OUT_BF16)
                    ((unsigned short*)C)[(size_t)row * ldc + col] = f32_to_bf16(v);
                else
                    ((float*)C)[(size_t)row * ldc + col] = v;
            }
}

// ---------------- causal flash attention, 8-wave supertiles, depth-2 pipeline ----------------
// __launch_bounds__(512, 2): VGPR cap 256 -> compiler allocates ~112, no spills; at 112
// VGPR the HW gives 4 waves/SIMD = 2 blocks/CU (the intended single-generation packing).
__global__ __launch_bounds__(512, 2) void attn8_kernel(const unsigned short* __restrict__ qkv,
                                                       unsigned short* __restrict__ attn,
                                                       unsigned short* __restrict__ Obuf,
                                                       float* __restrict__ mlbuf) {
    constexpr int T = 2048, HD3 = 3072, Cc = 1024;
    __shared__ __align__(16) unsigned short Ks[3][4096];  // [64 kv][64 d], col ^= (row&7)*8
    __shared__ __align__(16) unsigned short Vt[2][4096];  // [64 d][64 kv], col ^= ((d^(d>>3))&7)*8

    const int tid = threadIdx.x;
    const int lane = tid & 63;
    const int w = tid >> 6;          // 0..7
    const int l31 = lane & 31;
    const int hi = lane >> 5;

    const int bx = blockIdx.x;
    const int j = bx >> 5;            // 0..15 (LPT-ordered work item)
    const int bh = bx & 31;
    const int q = qS[j];              // supertile (256 q-rows)
    const int ts = tsS[j], te = teS[j];
    const int h = bh & 15;
    const int b = bh >> 4;
    const int q0w = q * 256 + w * 32;
    const int qrow = q0w + l31;
    const size_t base = (size_t)b * T * HD3;
    const int ntc = te - ts;          // >= 4 always

    bf16x8 qf[4];   // B-operand: lane holds Q[qrow][t*16 + hi*8 + jj] (q pre-scaled in GEMM1)
#pragma unroll
    for (int t = 0; t < 4; ++t)
        qf[t] = load_bf16x8(qkv + base + (size_t)qrow * HD3 + h * 64 + t * 16 + hi * 8);

    f32x16 acc0 = vzero16(), acc1 = vzero16();  // O^T: col=q(lane), row d = rr+8G+4hi (+32)
    float m = -3e38f, l = 0.f;

    ushort8 vA0, vB0;
// 512 threads: 1 x 16B gload_lds per thread stages a full 64x64 tile (8 KB).
#define LOADV(tile, r0) do { int kv0_ = (tile) * 64; \
    int rr0_ = tid >> 3, cc0_ = tid & 7; \
    r0 = *(const ushort8*)(qkv + base + (size_t)(kv0_ + rr0_) * HD3 + 2 * Cc + h * 64 + cc0_ * 8); } while (0)

#define DMAK(tile, kb) do { int kv0_ = (tile) * 64; \
    int row_ = tid >> 3; \
    int csw_ = (((tid & 7) * 8) ^ ((row_ & 7) * 8)); \
    gload_lds16(qkv + base + (size_t)(kv0_ + row_) * HD3 + Cc + h * 64 + csw_, \
                (void*)(((char*)&Ks[kb][0]) + tid * 16)); } while (0)

#define WRITEV(vb, r0) do { \
    int row_ = tid >> 3, cc_ = tid & 7; \
    _Pragma("unroll") for (int j_ = 0; j_ < 8; ++j_) { \
        int d_ = cc_ * 8 + j_; \
        int sw_ = ((d_ ^ (d_ >> 3)) & 7) * 8; \
        Vt[vb][d_ * 64 + (row_ ^ sw_)] = r0[j_]; } } while (0)

    // prologue: tile ts fully staged; tile ts+1 in flight
    LOADV(ts, vA0);
    DMAK(ts, 0);
    asm volatile("s_waitcnt vmcnt(0)" ::: "memory");
    __builtin_amdgcn_sched_barrier(0);
    WRITEV(0, vA0);
    LOADV(ts + 1, vB0);
    DMAK(ts + 1, 1);
    asm volatile("s_waitcnt lgkmcnt(0)" ::: "memory");
    __builtin_amdgcn_sched_barrier(0);
    __builtin_amdgcn_s_barrier();
    __builtin_amdgcn_sched_barrier(0);

    for (int tt = 0; tt < ntc; ++tt) {
        const int t = ts + tt;
        const int kv0 = t * 64;
        const int kcur = tt % 3;
        const int vcur = tt & 1;
        const bool act = (kv0 <= q0w + 31);
        const bool pre2 = (tt + 2) < ntc;

        // 1. write V(t+1) to LDS (regs 1 tile old -> implicit vmem wait here is free)
        if (tt + 1 < ntc) {
            if (tt & 1) WRITEV(vcur ^ 1, vA0); else WRITEV(vcur ^ 1, vB0);
        }
        // 2. issue prefetch for tile t+2 (V->regs, K->LDS buf (tt+2)%3)
        if (pre2) {
            if (tt & 1) LOADV(t + 2, vB0); else LOADV(t + 2, vA0);
            DMAK(t + 2, (tt + 2) % 3);
        }

        if (act) {
            f32x16 s0 = vzero16(), s1 = vzero16();
            bf16x8 pf[4];
            const bool st1_ok = (kv0 + 32 <= q0w + 31);
            __builtin_amdgcn_s_setprio(1);
#pragma unroll
            for (int tf = 0; tf < 4; ++tf) {  // st = 0
                int row = l31;
                int idx = kcur * 4096 + row * 64 + ((tf * 16 + hi * 8) ^ ((row & 7) * 8));
                s0 = __builtin_amdgcn_mfma_f32_32x32x16_bf16(load_bf16x8(&Ks[0][idx]), qf[tf], s0, 0, 0, 0);
            }
            if (st1_ok) {
#pragma unroll
                for (int tf = 0; tf < 4; ++tf) {  // st = 1
                    int row = 32 + l31;
                    int idx = kcur * 4096 + row * 64 + ((tf * 16 + hi * 8) ^ ((row & 7) * 8));
                    s1 = __builtin_amdgcn_mfma_f32_32x32x16_bf16(load_bf16x8(&Ks[0][idx]), qf[tf], s1, 0, 0, 0);
                }
            }
            __builtin_amdgcn_s_setprio(0);
            const bool needmask = (kv0 + 63 > q0w);
            if (needmask) {
#pragma unroll
                for (int G = 0; G < 4; ++G)
#pragma unroll
                    for (int rr = 0; rr < 4; ++rr) {
                        int kvb = kv0 + 8 * G + 4 * hi + rr;  // kv of C-reg (crow formula, HW-verified)
                        s0[G * 4 + rr] = (kvb      <= qrow) ? s0[G * 4 + rr] : -3e38f;
                        s1[G * 4 + rr] = (kvb + 32 <= qrow) ? s1[G * 4 + rr] : -3e38f;
                    }
            }
            float pmax = tmax32(s0, s1);
            pmax = fmaxf(pmax, __shfl_xor(pmax, 32));   // HW-verified exchange
            // defer-max (T13): skip O/l rescale while pmax - m <= 11.5 (log2 domain)
            if (!__all(pmax - m <= 11.5f)) {
                float mnew = fmaxf(m, pmax);
                float alpha = exp2f(m - mnew);
                m = mnew;
                l *= alpha;
#pragma unroll
                for (int i = 0; i < 16; ++i) { acc0[i] *= alpha; acc1[i] *= alpha; }
            }
#pragma unroll
            for (int i = 0; i < 16; ++i) {
                s0[i] = exp2f(s0[i] - m);
                s1[i] = exp2f(s1[i] - m);
            }

            // P -> B-fragments (cvt_pk + lane<->lane+32 exchange, HW-verified construction)
            unsigned pk0[4][2], pk1[4][2];
#pragma unroll
            for (int G = 0; G < 4; ++G) {
                pk0[G][0] = cvt_pk_bf16(s0[G * 4 + 0], s0[G * 4 + 1]);
                pk0[G][1] = cvt_pk_bf16(s0[G * 4 + 2], s0[G * 4 + 3]);
                pk1[G][0] = cvt_pk_bf16(s1[G * 4 + 0], s1[G * 4 + 1]);
                pk1[G][1] = cvt_pk_bf16(s1[G * 4 + 2], s1[G * 4 + 3]);
            }
#pragma unroll
            for (int tf = 0; tf < 4; ++tf) {
                const int kb = tf & 1;
                unsigned sA0, sA1, sB0, sB1;
                if (tf < 2) { sA0 = pk0[2 * kb][0]; sA1 = pk0[2 * kb][1]; sB0 = pk0[2 * kb + 1][0]; sB1 = pk0[2 * kb + 1][1]; }
                else        { sA0 = pk1[2 * kb][0]; sA1 = pk1[2 * kb][1]; sB0 = pk1[2 * kb + 1][0]; sB1 = pk1[2 * kb + 1][1]; }
                unsigned sd0 = hi ? sA0 : sB0, sd1 = hi ? sA1 : sB1;
                unsigned rc0 = (unsigned)__shfl_xor((int)sd0, 32);
                unsigned rc1 = (unsigned)__shfl_xor((int)sd1, 32);
                uint4v u;
                u[0] = hi ? rc0 : sA0;  u[1] = hi ? rc1 : sA1;   // k = hi*8 + 0..3
                u[2] = hi ? sB0 : rc0;  u[3] = hi ? sB1 : rc1;   // k = hi*8 + 4..7
                pf[tf] = __builtin_bit_cast(bf16x8, u);
            }

            __builtin_amdgcn_s_setprio(1);
#pragma unroll
            for (int tf = 0; tf < 4; ++tf) {
                {
                    int d = l31, sw = ((d ^ (d >> 3)) & 7) * 8;
                    bf16x8 vf = load_bf16x8(&Vt[vcur][d * 64 + ((tf * 16 + hi * 8) ^ sw)]);
                    acc0 = __builtin_amdgcn_mfma_f32_32x32x16_bf16(vf, pf[tf], acc0, 0, 0, 0);
                }
                {
                    int d = 32 + l31, sw = ((d ^ (d >> 3)) & 7) * 8;
                    bf16x8 vf = load_bf16x8(&Vt[vcur][d * 64 + ((tf * 16 + hi * 8) ^ sw)]);
                    acc1 = __builtin_amdgcn_mfma_f32_32x32x16_bf16(vf, pf[tf], acc1, 0, 0, 0);
                }
            }
            __builtin_amdgcn_s_setprio(0);

            // row-sum + l update off the PV critical path
            float rsum = tsum32(s0, s1);
            l += rsum + __shfl_xor(rsum, 32);
        }

        // counted-vmcnt barrier: guarantee K(t+1) landed, keep t+2 prefetch in flight
        if (pre2) asm volatile("s_waitcnt vmcnt(2) lgkmcnt(0)" ::: "memory");
        else      asm volatile("s_waitcnt vmcnt(0) lgkmcnt(0)" ::: "memory");
        __builtin_amdgcn_sched_barrier(0);
        __builtin_amdgcn_s_barrier();
        __builtin_amdgcn_sched_barrier(0);
    }

    const int mlq = mlS[j], obq = obS[j];
    const int qlocal = w * 32 + l31;   // 0..255
    if (mlq == 255) {
        // full supertile: normalize and write attn
        const float invl = 1.0f / l;
        const size_t ob = (size_t)b * T * Cc + (size_t)qrow * Cc + h * 64;
#pragma unroll
        for (int G = 0; G < 4; ++G) {
            ushort4v o0, o1;
#pragma unroll
            for (int rr = 0; rr < 4; ++rr) {
                o0[rr] = f32_to_bf16(acc0[G * 4 + rr] * invl);
                o1[rr] = f32_to_bf16(acc1[G * 4 + rr] * invl);
            }
            int d0 = 8 * G + 4 * hi;
            *(ushort4v*)(attn + ob + d0) = o0;
            *(ushort4v*)(attn + ob + 32 + d0) = o1;
        }
    } else {
        // chunk: write unnormalized partial O; c0 goes to attn natural location
        unsigned short* op = (obq == 255)
            ? (attn + (size_t)b * T * Cc + (size_t)qrow * Cc + h * 64)
            : (Obuf + (size_t)(bh * 8 + obq) * 16384 + qlocal * 64);
#pragma unroll
        for (int G = 0; G < 4; ++G) {
            ushort4v o0, o1;
#pragma unroll
            for (int rr = 0; rr < 4; ++rr) {
                o0[rr] = f32_to_bf16(acc0[G * 4 + rr]);
                o1[rr] = f32_to_bf16(acc1[G * 4 + rr]);
            }
            int d0 = 8 * G + 4 * hi;
            *(ushort4v*)(op + d0) = o0;
            *(ushort4v*)(op + 32 + d0) = o1;
        }
        if (hi == 0) {
            float* mp = mlbuf + (size_t)(bh * 13 + mlq) * 512 + qlocal * 2;
            mp[0] = m; mp[1] = l;
        }
    }
#undef LOADV
#undef DMAK
#undef WRITEV
}

// ---------------- combine: merge up to 4 kv-chunks of each split supertile ----------------
__global__ __launch_bounds__(256) void combine4_kernel(const unsigned short* __restrict__ Obuf,
                                                       const float* __restrict__ mlbuf,
                                                       unsigned short* __restrict__ attn) {
    constexpr int T = 2048, Cc = 1024;
    const int ss = blockIdx.x;            // 0..159: (bh, s)
    const int bh = ss / 5, s = ss - bh * 5;
    const int q = qs4[s];
    const int nc = ncs4[s], mlb = mlbs4[s], obb = obbs4[s];
    const int b = bh >> 4, h = bh & 15;
    const int qlocal = threadIdx.x;       // 0..255

    float mv[4], lv[4];
#pragma unroll
    for (int c = 0; c < 4; ++c) {
        mv[c] = -3e38f; lv[c] = 0.f;
        if (c < nc) {
            const float* mp = mlbuf + (size_t)(bh * 13 + mlb + c) * 512 + qlocal * 2;
            mv[c] = mp[0]; lv[c] = mp[1];
        }
    }
    float M = fmaxf(fmaxf(mv[0], mv[1]), fmaxf(mv[2], mv[3]));
    float fc[4];
    float denom = 0.f;
#pragma unroll
    for (int c = 0; c < 4; ++c) {
        fc[c] = (c < nc) ? exp2f(mv[c] - M) : 0.f;
        denom += fc[c] * lv[c];
    }
    const float inv = 1.f / denom;
#pragma unroll
    for (int c = 0; c < 4; ++c) fc[c] *= inv;

    unsigned short* po = attn + (size_t)b * T * Cc + (size_t)(q * 256 + qlocal) * Cc + h * 64;
#pragma unroll
    for (int i = 0; i < 8; ++i) {
        float acc[8] = {0.f, 0.f, 0.f, 0.f, 0.f, 0.f, 0.f, 0.f};
#pragma unroll
        for (int c = 0; c < 4; ++c) {
            if (c < nc) {
                const unsigned short* pc = (c == 0)
                    ? po
                    : (Obuf + (size_t)(bh * 8 + obb + c - 1) * 16384 + qlocal * 64);
                ushort8 a = *(const ushort8*)(pc + i * 8);
#pragma unroll
                for (int k = 0; k < 8; ++k) acc[k] += fc[c] * bf16_to_f32(a[k]);
            }
        }
        ushort8 o;
#pragma unroll
        for (int k = 0; k < 8; ++k) o[k] = f32_to_bf16(acc[k]);
        *(ushort8*)(po + i * 8) = o;
    }
}

extern "C" void kernel_launch(void* const* d_in, const int* in_sizes, int n_in,
                              void* d_out, int out_size, void* d_ws, size_t ws_size,
                              hipStream_t stream) {
    const float* x     = (const float*)d_in[0];
    // d_in[1] = mask (tril -> causal predicate), unused
    const float* w_qkv = (const float*)d_in[2];
    const float* w_out = (const float*)d_in[3];
    // d_in[4] = charge_w: provably no-op, unused
    float* out = (float*)d_out;

    // workspace (bf16 elements)
    unsigned short* xb     = (unsigned short*)d_ws;
    unsigned short* wqkvT  = xb + 4194304;        // [3072][1024]
    unsigned short* woutT  = wqkvT + 3145728;     // [1024][1024]
    unsigned short* qkv    = woutT + 1048576;     // [4096][3072]
    unsigned short* attn   = qkv + 12582912;      // [4096][1024]
    // partials alias regions dead after GEMM1: Obuf = 32bh x 8 slots x 16384 = 4194304
    // elements (exactly the xb region); mlbuf = 32 x 13 x 512 fp32 at wqkvT start.
    unsigned short* Obuf   = xb;
    float*          mlbuf  = (float*)wqkvT;

    cvt_kernel<<<2048, 256, 0, stream>>>(x, xb, 4194304);
    tcvt_kernel<<<dim3(96, 32), 256, 0, stream>>>(w_qkv, wqkvT, 1024, 3072);
    tcvt_kernel<<<dim3(32, 32), 256, 0, stream>>>(w_out, woutT, 1024, 1024);

    // qkv = xb @ w_qkv (M=4096, N=3072, K=1024), bf16 out, q-columns pre-scaled
    gemm_kernel<true, true><<<dim3(24, 32), 256, 0, stream>>>(xb, wqkvT, (void*)qkv, 1024, 3072);

    // causal attention: 512 LPT-ordered 8-wave blocks (16 supertile-chunks x 32 bh)
    attn8_kernel<<<512, 512, 0, stream>>>(qkv, attn, Obuf, mlbuf);
    combine4_kernel<<<160, 256, 0, stream>>>(Obuf, mlbuf, attn);

    // out = attn @ w_out (M=4096, N=1024, K=1024), fp32 out
    gemm_kernel<false, false><<<dim3(8, 32), 256, 0, stream>>>(attn, woutT, (void*)out, 1024, 1024);
}